// Round 4
// baseline (745.334 us; speedup 1.0000x reference)
//
#include <hip/hip_runtime.h>
#include <hip/hip_bf16.h>

typedef __hip_bfloat16 bf16;

__device__ __forceinline__ float b2f(bf16 v) { return __bfloat162float(v); }
__device__ __forceinline__ bf16 f2b(float v) { return __float2bfloat16(v); }
// unpack a dword holding two bf16 (little-endian: low halfword = lower address)
__device__ __forceinline__ void up2(unsigned u, float& lo, float& hi) {
  lo = __uint_as_float(u << 16);
  hi = __uint_as_float(u & 0xFFFF0000u);
}

// Runtime dtype detection (see previous version's rationale).
__device__ __forceinline__ bool detect_f32(const void* p) {
  const unsigned* u = (const unsigned*)p;
  int c = 0;
#pragma unroll
  for (int i = 0; i < 64; ++i) {
    unsigned e = (u[i] >> 7) & 0xFF;
    c += (e >= 170);
  }
  return c > 0;
}

__device__ __forceinline__ float ldp(const void* p, int i, bool f32) {
  return f32 ? ((const float*)p)[i] : b2f(((const bf16*)p)[i]);
}
__device__ __forceinline__ void ldpair(const void* p, size_t du, bool f32,
                                       float& a, float& b) {
  if (f32) {
    float2 v = ((const float2*)p)[du];
    a = v.x; b = v.y;
  } else {
    up2(((const unsigned*)p)[du], a, b);
  }
}
// 4 consecutive params starting at 4-aligned element index i
__device__ __forceinline__ void ld4(const void* p, size_t i, bool f32,
                                    float4& o) {
  if (f32) {
    o = ((const float4*)p)[i >> 2];
  } else {
    uint2 u = ((const uint2*)p)[i >> 2];
    up2(u.x, o.x, o.y);
    up2(u.y, o.z, o.w);
  }
}

#define SCALE 0.17677669529663687f

// ---------------------------------------------------------------------------
// Fused WT + cascaded 8-head windowed attention + relu/proj + IWT.
// v2 changes vs 617us baseline:
//  - XCD-bijective block swizzle: 64 consecutive windows per XCD (= its 32
//    CUs x 2 blocks) -> L2 write-combining of the 64B half-line writes.
//  - x-window + per-head weights register-prefetched one head ahead.
//  - softmax fused into S3 via wave-wide shfl_xor butterfly (attn rows are
//    lane-resident after S3); normalization deferred into S5 via inv_s.
//  - pw read directly from global (L2-resident, 8-lane broadcast) -> S6 gone.
//  - barriers per head: 8 -> 5; S7 overlaps next head's staging.
// ---------------------------------------------------------------------------
__global__ __launch_bounds__(256, 2) void fused_kernel(
    const void* __restrict__ x, const void* __restrict__ wtf,
    const void* __restrict__ iwtf,
    const void* __restrict__ dww, const void* __restrict__ dwb,
    const void* __restrict__ pw, const void* __restrict__ pb,
    const void* __restrict__ ab, const int* __restrict__ bidx,
    void* __restrict__ out) {
  __shared__ float lh_s[32 * 65];
  __shared__ float k_s[32 * 65];
  __shared__ float v_s[32 * 65];
  __shared__ float out_s[32 * 68];
  __shared__ float q_s[64 * 33];
  __shared__ float attn_s[64 * 65];
  __shared__ float w5_s[800];
  __shared__ float wf_s[512];
  __shared__ float ab_s[64];
  __shared__ float inv_s[64];

  const bool xf = detect_f32(x);   // x (and output) dtype
  const bool pf = detect_f32(pw);  // parameter dtype

  int t = threadIdx.x;
  // XCD-bijective swizzle: bid%8 = XCD (round-robin dispatch); give each XCD
  // a contiguous chunk of 64 windows so horizontally-adjacent windows share
  // an L2 -> half-line output writes combine into full 128B lines.
  int w = ((blockIdx.x & 7) << 6) | (blockIdx.x >> 3);
  int b = w >> 8, wi = w & 255, wy = wi >> 4, wx = wi & 15;

  float acc[8][8] = {};
  int to = t >> 3, tp = t & 7;
  int m = t & 63, ng = t >> 6;  // S3 roles: lane m, wave ng

  // bias gather indices are head-invariant: preload once into regs
  int bidx_r[16];
#pragma unroll
  for (int nn = 0; nn < 16; ++nn) bidx_r[nn] = bidx[(ng * 16 + nn) * 64 + m];

  // ---- head-0 prefetch: x window slice + weights into registers ----
  float X0[8], X1[8], X2[8], X3[8];
#pragma unroll
  for (int e = 0; e < 8; ++e) {
    int idx = t + 256 * e;
    int d = idx >> 6, p = idx & 63, r = p >> 3, cc = p & 7;
    int plane = b * 256 + d;  // h = 0
    size_t du = ((size_t)plane << 15) + ((wy * 16 + 2 * r) << 7) + wx * 8 + cc;
    ldpair(x, du, xf, X0[e], X1[e]);
    ldpair(x, du + 128, xf, X2[e], X3[e]);
  }
  float pwf0 = ldp(wtf, t, pf), pwf1 = ldp(wtf, 256 + t, pf);
  float pw5r[4];
#pragma unroll
  for (int e2 = 0; e2 < 4; ++e2) {
    int idx = t + 256 * e2;
    pw5r[e2] = (idx < 800) ? ldp(dww, idx, pf) : 0.f;
  }
  float pabr = (t < 64) ? ldp(ab, t, pf) : 0.f;

#pragma unroll 1
  for (int h = 0; h < 8; ++h) {
    // ---- S0: commit prefetched weights to LDS; issue next head's loads ----
    wf_s[t] = pwf0;
    wf_s[t + 256] = pwf1;
#pragma unroll
    for (int e2 = 0; e2 < 4; ++e2) {
      int idx = t + 256 * e2;
      if (idx < 800) w5_s[idx] = pw5r[e2];
    }
    if (t < 64) ab_s[t] = pabr;
    if (h < 7) {
      pwf0 = ldp(wtf, (h + 1) * 512 + t, pf);
      pwf1 = ldp(wtf, (h + 1) * 512 + 256 + t, pf);
#pragma unroll
      for (int e2 = 0; e2 < 4; ++e2) {
        int idx = t + 256 * e2;
        if (idx < 800) pw5r[e2] = ldp(dww, (h + 1) * 800 + idx, pf);
      }
      if (t < 64) pabr = ldp(ab, (h + 1) * 64 + t, pf);
    }
    __syncthreads();  // B_a: weights staged

    // ---- S1: WT -> lh / k(=hl) / v(=cascaded ll) from prefetched regs ----
#pragma unroll
    for (int e = 0; e < 8; ++e) {
      int idx = t + 256 * e;
      int d = idx >> 6, p = idx & 63;
      const float* f = wf_s + d * 16;
      float llv = X0[e] * f[0] + X1[e] * f[1] + X2[e] * f[2] + X3[e] * f[3];
      lh_s[d * 65 + p] = X0[e] * f[4] + X1[e] * f[5] + X2[e] * f[6] + X3[e] * f[7];
      k_s[d * 65 + p] = X0[e] * f[8] + X1[e] * f[9] + X2[e] * f[10] + X3[e] * f[11];
      if (h == 0)
        v_s[d * 65 + p] = llv;
      else
        v_s[d * 65 + p] = out_s[d * 68 + p] + llv;
    }
    // issue next head's x loads now; they complete during S2..S7
    if (h < 7) {
#pragma unroll
      for (int e = 0; e < 8; ++e) {
        int idx = t + 256 * e;
        int d = idx >> 6, p = idx & 63, r = p >> 3, cc = p & 7;
        int plane = b * 256 + (h + 1) * 32 + d;
        size_t du =
            ((size_t)plane << 15) + ((wy * 16 + 2 * r) << 7) + wx * 8 + cc;
        ldpair(x, du, xf, X0[e], X1[e]);
        ldpair(x, du + 128, xf, X2[e], X3[e]);
      }
    }
    __syncthreads();  // B_b: lh/k/v staged

    // ---- S2: q = zero-padded depthwise 5x5 conv over the 8x8 window ----
    {
      float dwbv = ldp(dwb, h * 32 + (t & 31), pf);  // d == t&31 for all e
#pragma unroll
      for (int e = 0; e < 8; ++e) {
        int idx = t + 256 * e;
        int d = idx & 31, n = idx >> 5;
        int r = n >> 3, cc = n & 7;
        float qa = dwbv;
        for (int u = 0; u < 5; ++u) {
          int rr = r + u - 2;
          if (rr < 0 || rr > 7) continue;
          for (int v = 0; v < 5; ++v) {
            int c2 = cc + v - 2;
            if (c2 < 0 || c2 > 7) continue;
            qa += lh_s[d * 65 + rr * 8 + c2] * w5_s[d * 25 + u * 5 + v];
          }
        }
        q_s[n * 33 + d] = qa;
      }
    }
    __syncthreads();  // B_c: q staged

    // ---- S3 + softmax (fused, in-register): wave ng owns rows ng*16.. ----
    // lane m holds column m of each row -> butterfly shfl reduce for max/sum;
    // store unnormalized exp, defer 1/sum into S5 via inv_s.
    {
      float kreg[32];
#pragma unroll
      for (int d = 0; d < 32; ++d) kreg[d] = k_s[d * 65 + m];
#pragma unroll
      for (int nn = 0; nn < 16; ++nn) {
        int n = ng * 16 + nn;
        float a2 = 0.f;
#pragma unroll
        for (int d = 0; d < 32; ++d) a2 += q_s[n * 33 + d] * kreg[d];
        a2 = a2 * SCALE + ab_s[bidx_r[nn]];
        float mx = a2;
#pragma unroll
        for (int msk = 32; msk > 0; msk >>= 1)
          mx = fmaxf(mx, __shfl_xor(mx, msk, 64));
        float e2 = __expf(a2 - mx);
        float sum = e2;
#pragma unroll
        for (int msk = 32; msk > 0; msk >>= 1) sum += __shfl_xor(sum, msk, 64);
        attn_s[n * 65 + m] = e2;
        if (m == 0) inv_s[n] = 1.f / sum;
      }
    }
    __syncthreads();  // B_d: attn (unnormalized) + inv staged

    // ---- S5: out[d][n] = inv[n] * sum_m v[d][m] attn[n][m] ----
    {
      int d = t & 31, n0 = (t >> 5) * 8;
      float pv[8] = {0, 0, 0, 0, 0, 0, 0, 0};
      for (int mm = 0; mm < 64; ++mm) {
        float vv = v_s[d * 65 + mm];
#pragma unroll
        for (int e = 0; e < 8; ++e) pv[e] += vv * attn_s[(n0 + e) * 65 + mm];
      }
#pragma unroll
      for (int e = 0; e < 8; ++e)
        out_s[d * 68 + n0 + e] = pv[e] * inv_s[n0 + e];
    }
    __syncthreads();  // B_e: out_s published

    // ---- S7: proj accumulate, pw direct from global (L2-resident) ----
    // acc[o][p] += pw[o][k] * relu(out_s[k][p]); no trailing barrier: S7
    // overlaps next head's S0 staging and prefetch issue.
#pragma unroll 1
    for (int q4 = 0; q4 < 8; ++q4) {
      float4 w4[8];
#pragma unroll
      for (int i2 = 0; i2 < 8; ++i2)
        ld4(pw, (size_t)(to + 32 * i2) * 256 + h * 32 + q4 * 4, pf, w4[i2]);
#pragma unroll
      for (int j = 0; j < 4; ++j) {
        int kk = q4 * 4 + j;
        float r[8];
#pragma unroll
        for (int pi = 0; pi < 8; ++pi)
          r[pi] = fmaxf(out_s[kk * 68 + tp + 8 * pi], 0.f);
#pragma unroll
        for (int i2 = 0; i2 < 8; ++i2) {
          float wv = (j == 0)   ? w4[i2].x
                     : (j == 1) ? w4[i2].y
                     : (j == 2) ? w4[i2].z
                                : w4[i2].w;
#pragma unroll
          for (int pi = 0; pi < 8; ++pi) acc[i2][pi] += wv * r[pi];
        }
      }
    }
    // no barrier here (see hazard analysis: all LDS buffers S7/S0/S1 touch
    // are protected by B_a..B_e of the next iteration)
  }

  // ---- Epilogue: +bias, then IWT directly to out (write-only, paired) ----
#pragma unroll 1
  for (int i2 = 0; i2 < 8; ++i2) {
    int o = to + 32 * i2;
    float pbv = ldp(pb, o, pf);
    float f[16], g[16];
#pragma unroll
    for (int e = 0; e < 16; ++e) {
      f[e] = ldp(wtf, o * 16 + e, pf);
      g[e] = ldp(iwtf, o * 16 + e, pf);
    }
    int plane = b * 256 + o;
#pragma unroll
    for (int pi = 0; pi < 8; ++pi) {
      int y = wy * 8 + pi;   // band row
      int xb = wx * 8 + tp;  // band col (== x/out pair-column index)
      float llv = acc[i2][pi] + pbv;
      size_t du = ((size_t)plane << 15) + ((size_t)(2 * y) << 7) + xb;
      float x00, x01, x10, x11;
      ldpair(x, du, xf, x00, x01);
      ldpair(x, du + 128, xf, x10, x11);
      float lhv = x00 * f[4] + x01 * f[5] + x10 * f[6] + x11 * f[7];
      float hlv = x00 * f[8] + x01 * f[9] + x10 * f[10] + x11 * f[11];
      float hhv = x00 * f[12] + x01 * f[13] + x10 * f[14] + x11 * f[15];
#pragma unroll
      for (int sy = 0; sy < 2; ++sy) {
        float v0 = llv * g[0 + sy * 2] + lhv * g[4 + sy * 2] +
                   hlv * g[8 + sy * 2] + hhv * g[12 + sy * 2];
        float v1 = llv * g[1 + sy * 2] + lhv * g[5 + sy * 2] +
                   hlv * g[9 + sy * 2] + hhv * g[13 + sy * 2];
        size_t oi = ((size_t)plane << 15) + ((size_t)(2 * y + sy) << 7) + xb;
        if (xf) {
          ((float2*)out)[oi] = make_float2(v0, v1);
        } else {
          union { bf16 hh2[2]; unsigned u; } pk;
          pk.hh2[0] = f2b(v0);
          pk.hh2[1] = f2b(v1);
          ((unsigned*)out)[oi] = pk.u;
        }
      }
    }
  }
}

extern "C" void kernel_launch(void* const* d_in, const int* in_sizes, int n_in,
                              void* d_out, int out_size, void* d_ws, size_t ws_size,
                              hipStream_t stream) {
  // Expected dict-order element counts:
  // x=33554432, wtf=4096, iwtf=4096, dww=6400, dwb=256, pw=65536, pb=256,
  // ab=512, bidx=4096
  const void *x, *wtf, *iwtf, *dww, *dwb, *pw, *pb, *ab;
  const int* bidx;
  if (in_sizes[0] == 33554432) {  // setup_inputs() dict order
    x = d_in[0]; wtf = d_in[1]; iwtf = d_in[2]; dww = d_in[3]; dwb = d_in[4];
    pw = d_in[5]; pb = d_in[6]; ab = d_in[7]; bidx = (const int*)d_in[8];
  } else if (in_sizes[0] == 512) {  // alphabetical order
    ab = d_in[0]; bidx = (const int*)d_in[1]; dwb = d_in[2]; dww = d_in[3];
    iwtf = d_in[4]; pb = d_in[5]; pw = d_in[6]; wtf = d_in[7]; x = d_in[8];
  } else {  // reversed dict order
    bidx = (const int*)d_in[0]; ab = d_in[1]; pb = d_in[2]; pw = d_in[3];
    dwb = d_in[4]; dww = d_in[5]; iwtf = d_in[6]; wtf = d_in[7]; x = d_in[8];
  }

  fused_kernel<<<512, 256, 0, stream>>>(x, wtf, iwtf, dww, dwb, pw, pb, ab,
                                        bidx, d_out);
}

// Round 7
// 593.201 us; speedup vs baseline: 1.2565x; 1.2565x over previous
//
#include <hip/hip_runtime.h>
#include <hip/hip_bf16.h>

typedef __hip_bfloat16 bf16;

__device__ __forceinline__ float b2f(bf16 v) { return __bfloat162float(v); }
__device__ __forceinline__ bf16 f2b(float v) { return __float2bfloat16(v); }
// unpack a dword holding two bf16 (little-endian: low halfword = lower address)
__device__ __forceinline__ void up2(unsigned u, float& lo, float& hi) {
  lo = __uint_as_float(u << 16);
  hi = __uint_as_float(u & 0xFFFF0000u);
}

// Runtime dtype detection (see previous version's rationale).
__device__ __forceinline__ bool detect_f32(const void* p) {
  const unsigned* u = (const unsigned*)p;
  int c = 0;
#pragma unroll
  for (int i = 0; i < 64; ++i) {
    unsigned e = (u[i] >> 7) & 0xFF;
    c += (e >= 170);
  }
  return c > 0;
}

__device__ __forceinline__ float ldp(const void* p, int i, bool f32) {
  return f32 ? ((const float*)p)[i] : b2f(((const bf16*)p)[i]);
}
__device__ __forceinline__ void ldpair(const void* p, size_t du, bool f32,
                                       float& a, float& b) {
  if (f32) {
    float2 v = ((const float2*)p)[du];
    a = v.x; b = v.y;
  } else {
    up2(((const unsigned*)p)[du], a, b);
  }
}
// 4 consecutive params starting at 4-aligned element index i
__device__ __forceinline__ void ld4(const void* p, size_t i, bool f32,
                                    float4& o) {
  if (f32) {
    o = ((const float4*)p)[i >> 2];
  } else {
    uint2 u = ((const uint2*)p)[i >> 2];
    up2(u.x, o.x, o.y);
    up2(u.y, o.z, o.w);
  }
}

#define SCALE 0.17677669529663687f

// ---------------------------------------------------------------------------
// Fused WT + cascaded 8-head windowed attention + relu/proj + IWT.
// v3 (post-mortem of v2's 600us regression vs 460us baseline):
//  - REVERTED: XCD swizzle (WRITE_SIZE went UP 426->476MB -> wrong dispatch
//    assumption). Identity window mapping again.
//  - REVERTED: full-loop x-register prefetch + bidx_r pinning (live set
//    ~150 > 128 VGPR -> in-loop spill; +50MB HBM write = scratch dirty
//    evictions, VALUBusy down with dur up = spill stalls).
//  - KEPT from v2: weight reg-prefetch (7 regs), shfl-butterfly softmax
//    fused into S3 (bank conflicts 524K->0) with deferred 1/sum via inv_s,
//    pw read direct from global in S7 (absmax improved 2x), 5 barriers/head
//    (was 8), no trailing barrier after S7.
// Peak live set ~110 VGPR -> no spill expected.
// ---------------------------------------------------------------------------
__global__ __launch_bounds__(256, 2) void fused_kernel(
    const void* __restrict__ x, const void* __restrict__ wtf,
    const void* __restrict__ iwtf,
    const void* __restrict__ dww, const void* __restrict__ dwb,
    const void* __restrict__ pw, const void* __restrict__ pb,
    const void* __restrict__ ab, const int* __restrict__ bidx,
    void* __restrict__ out) {
  __shared__ float lh_s[32 * 65];
  __shared__ float k_s[32 * 65];
  __shared__ float v_s[32 * 65];
  __shared__ float out_s[32 * 68];
  __shared__ float q_s[64 * 33];
  __shared__ float attn_s[64 * 65];
  __shared__ float w5_s[800];
  __shared__ float wf_s[512];
  __shared__ float ab_s[64];
  __shared__ float inv_s[64];

  const bool xf = detect_f32(x);   // x (and output) dtype
  const bool pf = detect_f32(pw);  // parameter dtype

  int t = threadIdx.x;
  int w = blockIdx.x;  // identity mapping (v2 swizzle reverted)
  int b = w >> 8, wi = w & 255, wy = wi >> 4, wx = wi & 15;

  float acc[8][8] = {};
  int to = t >> 3, tp = t & 7;
  int m = t & 63, ng = t >> 6;  // S3 roles: lane m, wave ng

  // ---- weight prefetch for head 0 (7 regs, cheap) ----
  float pwf0 = ldp(wtf, t, pf), pwf1 = ldp(wtf, 256 + t, pf);
  float pw5r[4];
#pragma unroll
  for (int e2 = 0; e2 < 4; ++e2) {
    int idx = t + 256 * e2;
    pw5r[e2] = (idx < 800) ? ldp(dww, idx, pf) : 0.f;
  }
  float pabr = (t < 64) ? ldp(ab, t, pf) : 0.f;

#pragma unroll 1
  for (int h = 0; h < 8; ++h) {
    // ---- S0: commit prefetched weights to LDS; issue next head's ----
    wf_s[t] = pwf0;
    wf_s[t + 256] = pwf1;
#pragma unroll
    for (int e2 = 0; e2 < 4; ++e2) {
      int idx = t + 256 * e2;
      if (idx < 800) w5_s[idx] = pw5r[e2];
    }
    if (t < 64) ab_s[t] = pabr;
    if (h < 7) {
      pwf0 = ldp(wtf, (h + 1) * 512 + t, pf);
      pwf1 = ldp(wtf, (h + 1) * 512 + 256 + t, pf);
#pragma unroll
      for (int e2 = 0; e2 < 4; ++e2) {
        int idx = t + 256 * e2;
        if (idx < 800) pw5r[e2] = ldp(dww, (h + 1) * 800 + idx, pf);
      }
      if (t < 64) pabr = ldp(ab, (h + 1) * 64 + t, pf);
    }
    __syncthreads();  // B_a: weights staged

    // ---- S1: fused WT -> lh / k(=hl) / v(=cascaded ll), x loaded here ----
#pragma unroll
    for (int e = 0; e < 8; ++e) {
      int idx = t + 256 * e;
      int d = idx >> 6, p = idx & 63, r = p >> 3, cc = p & 7;
      int plane = b * 256 + h * 32 + d;
      size_t du =
          ((size_t)plane << 15) + ((wy * 16 + 2 * r) << 7) + wx * 8 + cc;
      float x00, x01, x10, x11;
      ldpair(x, du, xf, x00, x01);
      ldpair(x, du + 128, xf, x10, x11);
      const float* f = wf_s + d * 16;
      float llv = x00 * f[0] + x01 * f[1] + x10 * f[2] + x11 * f[3];
      lh_s[d * 65 + p] = x00 * f[4] + x01 * f[5] + x10 * f[6] + x11 * f[7];
      k_s[d * 65 + p] = x00 * f[8] + x01 * f[9] + x10 * f[10] + x11 * f[11];
      if (h == 0)
        v_s[d * 65 + p] = llv;
      else
        v_s[d * 65 + p] = out_s[d * 68 + p] + llv;
    }
    __syncthreads();  // B_b: lh/k/v staged

    // ---- S2: q = zero-padded depthwise 5x5 conv over the 8x8 window ----
    {
      float dwbv = ldp(dwb, h * 32 + (t & 31), pf);  // d == t&31 for all e
#pragma unroll
      for (int e = 0; e < 8; ++e) {
        int idx = t + 256 * e;
        int d = idx & 31, n = idx >> 5;
        int r = n >> 3, cc = n & 7;
        float qa = dwbv;
        for (int u = 0; u < 5; ++u) {
          int rr = r + u - 2;
          if (rr < 0 || rr > 7) continue;
          for (int v = 0; v < 5; ++v) {
            int c2 = cc + v - 2;
            if (c2 < 0 || c2 > 7) continue;
            qa += lh_s[d * 65 + rr * 8 + c2] * w5_s[d * 25 + u * 5 + v];
          }
        }
        q_s[n * 33 + d] = qa;
      }
    }
    __syncthreads();  // B_c: q staged

    // ---- S3 + softmax (fused, in-register): wave ng owns rows ng*16.. ----
    // lane m holds column m of each row -> butterfly shfl reduce for max/sum;
    // store unnormalized exp, defer 1/sum into S5 via inv_s.
    {
      float kreg[32];
#pragma unroll
      for (int d = 0; d < 32; ++d) kreg[d] = k_s[d * 65 + m];
#pragma unroll
      for (int nn = 0; nn < 16; ++nn) {
        int n = ng * 16 + nn;
        float a2 = 0.f;
#pragma unroll
        for (int d = 0; d < 32; ++d) a2 += q_s[n * 33 + d] * kreg[d];
        a2 = a2 * SCALE + ab_s[bidx[n * 64 + m]];
        float mx = a2;
#pragma unroll
        for (int msk = 32; msk > 0; msk >>= 1)
          mx = fmaxf(mx, __shfl_xor(mx, msk, 64));
        float e2 = __expf(a2 - mx);
        float sum = e2;
#pragma unroll
        for (int msk = 32; msk > 0; msk >>= 1) sum += __shfl_xor(sum, msk, 64);
        attn_s[n * 65 + m] = e2;
        if (m == 0) inv_s[n] = 1.f / sum;
      }
    }
    __syncthreads();  // B_d: attn (unnormalized) + inv staged

    // ---- S5: out[d][n] = inv[n] * sum_m v[d][m] attn[n][m] ----
    {
      int d = t & 31, n0 = (t >> 5) * 8;
      float pv[8] = {0, 0, 0, 0, 0, 0, 0, 0};
      for (int mm = 0; mm < 64; ++mm) {
        float vv = v_s[d * 65 + mm];
#pragma unroll
        for (int e = 0; e < 8; ++e) pv[e] += vv * attn_s[(n0 + e) * 65 + mm];
      }
#pragma unroll
      for (int e = 0; e < 8; ++e)
        out_s[d * 68 + n0 + e] = pv[e] * inv_s[n0 + e];
    }
    __syncthreads();  // B_e: out_s published

    // ---- S7: proj accumulate, pw direct from global (L2-resident) ----
    // acc[o][p] += pw[o][k] * relu(out_s[k][p]); no trailing barrier: next
    // iteration's S0 touches only wf_s/w5_s/ab_s which S7 never reads, and
    // B_a fences before S1.
#pragma unroll 1
    for (int q4 = 0; q4 < 8; ++q4) {
      float4 w4[8];
#pragma unroll
      for (int i2 = 0; i2 < 8; ++i2)
        ld4(pw, (size_t)(to + 32 * i2) * 256 + h * 32 + q4 * 4, pf, w4[i2]);
#pragma unroll
      for (int j = 0; j < 4; ++j) {
        int kk = q4 * 4 + j;
        float r[8];
#pragma unroll
        for (int pi = 0; pi < 8; ++pi)
          r[pi] = fmaxf(out_s[kk * 68 + tp + 8 * pi], 0.f);
#pragma unroll
        for (int i2 = 0; i2 < 8; ++i2) {
          float wv = (j == 0)   ? w4[i2].x
                     : (j == 1) ? w4[i2].y
                     : (j == 2) ? w4[i2].z
                                : w4[i2].w;
#pragma unroll
          for (int pi = 0; pi < 8; ++pi) acc[i2][pi] += wv * r[pi];
        }
      }
    }
  }

  // ---- Epilogue: +bias, then IWT directly to out (write-only, paired) ----
#pragma unroll 1
  for (int i2 = 0; i2 < 8; ++i2) {
    int o = to + 32 * i2;
    float pbv = ldp(pb, o, pf);
    float f[16], g[16];
#pragma unroll
    for (int e = 0; e < 16; ++e) {
      f[e] = ldp(wtf, o * 16 + e, pf);
      g[e] = ldp(iwtf, o * 16 + e, pf);
    }
    int plane = b * 256 + o;
#pragma unroll
    for (int pi = 0; pi < 8; ++pi) {
      int y = wy * 8 + pi;   // band row
      int xb = wx * 8 + tp;  // band col (== x/out pair-column index)
      float llv = acc[i2][pi] + pbv;
      size_t du = ((size_t)plane << 15) + ((size_t)(2 * y) << 7) + xb;
      float x00, x01, x10, x11;
      ldpair(x, du, xf, x00, x01);
      ldpair(x, du + 128, xf, x10, x11);
      float lhv = x00 * f[4] + x01 * f[5] + x10 * f[6] + x11 * f[7];
      float hlv = x00 * f[8] + x01 * f[9] + x10 * f[10] + x11 * f[11];
      float hhv = x00 * f[12] + x01 * f[13] + x10 * f[14] + x11 * f[15];
#pragma unroll
      for (int sy = 0; sy < 2; ++sy) {
        float v0 = llv * g[0 + sy * 2] + lhv * g[4 + sy * 2] +
                   hlv * g[8 + sy * 2] + hhv * g[12 + sy * 2];
        float v1 = llv * g[1 + sy * 2] + lhv * g[5 + sy * 2] +
                   hlv * g[9 + sy * 2] + hhv * g[13 + sy * 2];
        size_t oi = ((size_t)plane << 15) + ((size_t)(2 * y + sy) << 7) + xb;
        if (xf) {
          ((float2*)out)[oi] = make_float2(v0, v1);
        } else {
          union { bf16 hh2[2]; unsigned u; } pk;
          pk.hh2[0] = f2b(v0);
          pk.hh2[1] = f2b(v1);
          ((unsigned*)out)[oi] = pk.u;
        }
      }
    }
  }
}

extern "C" void kernel_launch(void* const* d_in, const int* in_sizes, int n_in,
                              void* d_out, int out_size, void* d_ws, size_t ws_size,
                              hipStream_t stream) {
  // Expected dict-order element counts:
  // x=33554432, wtf=4096, iwtf=4096, dww=6400, dwb=256, pw=65536, pb=256,
  // ab=512, bidx=4096
  const void *x, *wtf, *iwtf, *dww, *dwb, *pw, *pb, *ab;
  const int* bidx;
  if (in_sizes[0] == 33554432) {  // setup_inputs() dict order
    x = d_in[0]; wtf = d_in[1]; iwtf = d_in[2]; dww = d_in[3]; dwb = d_in[4];
    pw = d_in[5]; pb = d_in[6]; ab = d_in[7]; bidx = (const int*)d_in[8];
  } else if (in_sizes[0] == 512) {  // alphabetical order
    ab = d_in[0]; bidx = (const int*)d_in[1]; dwb = d_in[2]; dww = d_in[3];
    iwtf = d_in[4]; pb = d_in[5]; pw = d_in[6]; wtf = d_in[7]; x = d_in[8];
  } else {  // reversed dict order
    bidx = (const int*)d_in[0]; ab = d_in[1]; pb = d_in[2]; pw = d_in[3];
    dwb = d_in[4]; dww = d_in[5]; iwtf = d_in[6]; wtf = d_in[7]; x = d_in[8];
  }

  fused_kernel<<<512, 256, 0, stream>>>(x, wtf, iwtf, dww, dwb, pw, pb, ab,
                                        bidx, d_out);
}

// Round 13
// 549.587 us; speedup vs baseline: 1.3562x; 1.0794x over previous
//
#include <hip/hip_runtime.h>
#include <hip/hip_bf16.h>

typedef __hip_bfloat16 bf16;

__device__ __forceinline__ float b2f(bf16 v) { return __bfloat162float(v); }
__device__ __forceinline__ bf16 f2b(float v) { return __float2bfloat16(v); }
// unpack a dword holding two bf16 (little-endian: low halfword = lower address)
__device__ __forceinline__ void up2(unsigned u, float& lo, float& hi) {
  lo = __uint_as_float(u << 16);
  hi = __uint_as_float(u & 0xFFFF0000u);
}

// Runtime dtype detection (see previous version's rationale).
__device__ __forceinline__ bool detect_f32(const void* p) {
  const unsigned* u = (const unsigned*)p;
  int c = 0;
#pragma unroll
  for (int i = 0; i < 64; ++i) {
    unsigned e = (u[i] >> 7) & 0xFF;
    c += (e >= 170);
  }
  return c > 0;
}

__device__ __forceinline__ float ldp(const void* p, int i, bool f32) {
  return f32 ? ((const float*)p)[i] : b2f(((const bf16*)p)[i]);
}
__device__ __forceinline__ void ldpair(const void* p, size_t du, bool f32,
                                       float& a, float& b) {
  if (f32) {
    float2 v = ((const float2*)p)[du];
    a = v.x; b = v.y;
  } else {
    up2(((const unsigned*)p)[du], a, b);
  }
}
// 4 consecutive params starting at 4-aligned element index i
__device__ __forceinline__ void ld4(const void* p, size_t i, bool f32,
                                    float4& o) {
  if (f32) {
    o = ((const float4*)p)[i >> 2];
  } else {
    uint2 u = ((const uint2*)p)[i >> 2];
    up2(u.x, o.x, o.y);
    up2(u.y, o.z, o.w);
  }
}

#define SCALE 0.17677669529663687f

// ---------------------------------------------------------------------------
// Fused WT + cascaded 8-head windowed attention + relu/proj + IWT.
// v4 (v3 post-mortem: 441us rocprof, VALUBusy 27%, HBM 24%, Occ 22% -- all
// pipes idle ~75% => latency-bound at 8 waves/CU; grid 512 blocks = 2/CU is
// the cap, so LDS diets are moot):
//  - 256 -> 512 threads per block (same 512 blocks, one per window).
//    2 blocks x 8 waves = 16 waves/CU (50% occ). Per-thread work halves in
//    every phase; acc 64->32 regs. Algorithm, barriers, LDS layout unchanged.
//  - from v3: weight reg-prefetch, shfl-butterfly softmax fused into S3
//    (deferred 1/sum via inv_s), pw direct from global in S7, 5 barriers/head,
//    no trailing barrier after S7.
// ---------------------------------------------------------------------------
__global__ __launch_bounds__(512, 4) void fused_kernel(
    const void* __restrict__ x, const void* __restrict__ wtf,
    const void* __restrict__ iwtf,
    const void* __restrict__ dww, const void* __restrict__ dwb,
    const void* __restrict__ pw, const void* __restrict__ pb,
    const void* __restrict__ ab, const int* __restrict__ bidx,
    void* __restrict__ out) {
  __shared__ float lh_s[32 * 65];
  __shared__ float k_s[32 * 65];
  __shared__ float v_s[32 * 65];
  __shared__ float out_s[32 * 68];
  __shared__ float q_s[64 * 33];
  __shared__ float attn_s[64 * 65];
  __shared__ float w5_s[800];
  __shared__ float wf_s[512];
  __shared__ float ab_s[64];
  __shared__ float inv_s[64];

  const bool xf = detect_f32(x);   // x (and output) dtype
  const bool pf = detect_f32(pw);  // parameter dtype

  int t = threadIdx.x;  // 0..511
  int w = blockIdx.x;   // identity mapping
  int b = w >> 8, wi = w & 255, wy = wi >> 4, wx = wi & 15;

  float acc[4][8] = {};
  int to = t >> 3, tp = t & 7;  // to 0..63, tp 0..7 (S7/epilogue roles)
  int m = t & 63, ng = t >> 6;  // S3 roles: lane m, wave ng (0..7)

  // ---- weight prefetch for head 0 (4 regs, cheap) ----
  float pwf0 = ldp(wtf, t, pf);
  float pw5r[2];
#pragma unroll
  for (int e2 = 0; e2 < 2; ++e2) {
    int idx = t + 512 * e2;
    pw5r[e2] = (idx < 800) ? ldp(dww, idx, pf) : 0.f;
  }
  float pabr = (t < 64) ? ldp(ab, t, pf) : 0.f;

#pragma unroll 1
  for (int h = 0; h < 8; ++h) {
    // ---- S0: commit prefetched weights to LDS; issue next head's ----
    wf_s[t] = pwf0;
#pragma unroll
    for (int e2 = 0; e2 < 2; ++e2) {
      int idx = t + 512 * e2;
      if (idx < 800) w5_s[idx] = pw5r[e2];
    }
    if (t < 64) ab_s[t] = pabr;
    if (h < 7) {
      pwf0 = ldp(wtf, (h + 1) * 512 + t, pf);
#pragma unroll
      for (int e2 = 0; e2 < 2; ++e2) {
        int idx = t + 512 * e2;
        if (idx < 800) pw5r[e2] = ldp(dww, (h + 1) * 800 + idx, pf);
      }
      if (t < 64) pabr = ldp(ab, (h + 1) * 64 + t, pf);
    }
    __syncthreads();  // B_a: weights staged

    // ---- S1: fused WT -> lh / k(=hl) / v(=cascaded ll), x loaded here ----
#pragma unroll
    for (int e = 0; e < 4; ++e) {
      int idx = t + 512 * e;
      int d = idx >> 6, p = idx & 63, r = p >> 3, cc = p & 7;
      int plane = b * 256 + h * 32 + d;
      size_t du =
          ((size_t)plane << 15) + ((wy * 16 + 2 * r) << 7) + wx * 8 + cc;
      float x00, x01, x10, x11;
      ldpair(x, du, xf, x00, x01);
      ldpair(x, du + 128, xf, x10, x11);
      const float* f = wf_s + d * 16;
      float llv = x00 * f[0] + x01 * f[1] + x10 * f[2] + x11 * f[3];
      lh_s[d * 65 + p] = x00 * f[4] + x01 * f[5] + x10 * f[6] + x11 * f[7];
      k_s[d * 65 + p] = x00 * f[8] + x01 * f[9] + x10 * f[10] + x11 * f[11];
      if (h == 0)
        v_s[d * 65 + p] = llv;
      else
        v_s[d * 65 + p] = out_s[d * 68 + p] + llv;
    }
    __syncthreads();  // B_b: lh/k/v staged

    // ---- S2: q = zero-padded depthwise 5x5 conv over the 8x8 window ----
    {
      float dwbv = ldp(dwb, h * 32 + (t & 31), pf);  // d == t&31 for all e
#pragma unroll
      for (int e = 0; e < 4; ++e) {
        int idx = t + 512 * e;
        int d = idx & 31, n = idx >> 5;
        int r = n >> 3, cc = n & 7;
        float qa = dwbv;
        for (int u = 0; u < 5; ++u) {
          int rr = r + u - 2;
          if (rr < 0 || rr > 7) continue;
          for (int v = 0; v < 5; ++v) {
            int c2 = cc + v - 2;
            if (c2 < 0 || c2 > 7) continue;
            qa += lh_s[d * 65 + rr * 8 + c2] * w5_s[d * 25 + u * 5 + v];
          }
        }
        q_s[n * 33 + d] = qa;
      }
    }
    __syncthreads();  // B_c: q staged

    // ---- S3 + softmax (fused, in-register): wave ng owns rows ng*8.. ----
    // lane m holds column m of each row -> butterfly shfl reduce for max/sum;
    // store unnormalized exp, defer 1/sum into S5 via inv_s.
    {
      float kreg[32];
#pragma unroll
      for (int d = 0; d < 32; ++d) kreg[d] = k_s[d * 65 + m];
#pragma unroll
      for (int nn = 0; nn < 8; ++nn) {
        int n = ng * 8 + nn;
        float a2 = 0.f;
#pragma unroll
        for (int d = 0; d < 32; ++d) a2 += q_s[n * 33 + d] * kreg[d];
        a2 = a2 * SCALE + ab_s[bidx[n * 64 + m]];
        float mx = a2;
#pragma unroll
        for (int msk = 32; msk > 0; msk >>= 1)
          mx = fmaxf(mx, __shfl_xor(mx, msk, 64));
        float e2 = __expf(a2 - mx);
        float sum = e2;
#pragma unroll
        for (int msk = 32; msk > 0; msk >>= 1) sum += __shfl_xor(sum, msk, 64);
        attn_s[n * 65 + m] = e2;
        if (m == 0) inv_s[n] = 1.f / sum;
      }
    }
    __syncthreads();  // B_d: attn (unnormalized) + inv staged

    // ---- S5: out[d][n] = inv[n] * sum_m v[d][m] attn[n][m] ----
    {
      int d = t & 31, n0 = (t >> 5) * 4;
      float pv[4] = {0, 0, 0, 0};
      for (int mm = 0; mm < 64; ++mm) {
        float vv = v_s[d * 65 + mm];
#pragma unroll
        for (int e = 0; e < 4; ++e) pv[e] += vv * attn_s[(n0 + e) * 65 + mm];
      }
#pragma unroll
      for (int e = 0; e < 4; ++e)
        out_s[d * 68 + n0 + e] = pv[e] * inv_s[n0 + e];
    }
    __syncthreads();  // B_e: out_s published

    // ---- S7: proj accumulate, pw direct from global (L2-resident) ----
    // acc[o][p] += pw[o][k] * relu(out_s[k][p]); no trailing barrier: next
    // iteration's S0 touches only wf_s/w5_s/ab_s which S7 never reads, and
    // B_a fences before S1.
#pragma unroll 1
    for (int q4 = 0; q4 < 8; ++q4) {
      float4 w4[4];
#pragma unroll
      for (int i2 = 0; i2 < 4; ++i2)
        ld4(pw, (size_t)(to + 64 * i2) * 256 + h * 32 + q4 * 4, pf, w4[i2]);
#pragma unroll
      for (int j = 0; j < 4; ++j) {
        int kk = q4 * 4 + j;
        float r[8];
#pragma unroll
        for (int pi = 0; pi < 8; ++pi)
          r[pi] = fmaxf(out_s[kk * 68 + tp + 8 * pi], 0.f);
#pragma unroll
        for (int i2 = 0; i2 < 4; ++i2) {
          float wv = (j == 0)   ? w4[i2].x
                     : (j == 1) ? w4[i2].y
                     : (j == 2) ? w4[i2].z
                                : w4[i2].w;
#pragma unroll
          for (int pi = 0; pi < 8; ++pi) acc[i2][pi] += wv * r[pi];
        }
      }
    }
  }

  // ---- Epilogue: +bias, then IWT directly to out (write-only, paired) ----
#pragma unroll 1
  for (int i2 = 0; i2 < 4; ++i2) {
    int o = to + 64 * i2;
    float pbv = ldp(pb, o, pf);
    float f[16], g[16];
#pragma unroll
    for (int e = 0; e < 16; ++e) {
      f[e] = ldp(wtf, o * 16 + e, pf);
      g[e] = ldp(iwtf, o * 16 + e, pf);
    }
    int plane = b * 256 + o;
#pragma unroll
    for (int pi = 0; pi < 8; ++pi) {
      int y = wy * 8 + pi;   // band row
      int xb = wx * 8 + tp;  // band col (== x/out pair-column index)
      float llv = acc[i2][pi] + pbv;
      size_t du = ((size_t)plane << 15) + ((size_t)(2 * y) << 7) + xb;
      float x00, x01, x10, x11;
      ldpair(x, du, xf, x00, x01);
      ldpair(x, du + 128, xf, x10, x11);
      float lhv = x00 * f[4] + x01 * f[5] + x10 * f[6] + x11 * f[7];
      float hlv = x00 * f[8] + x01 * f[9] + x10 * f[10] + x11 * f[11];
      float hhv = x00 * f[12] + x01 * f[13] + x10 * f[14] + x11 * f[15];
#pragma unroll
      for (int sy = 0; sy < 2; ++sy) {
        float v0 = llv * g[0 + sy * 2] + lhv * g[4 + sy * 2] +
                   hlv * g[8 + sy * 2] + hhv * g[12 + sy * 2];
        float v1 = llv * g[1 + sy * 2] + lhv * g[5 + sy * 2] +
                   hlv * g[9 + sy * 2] + hhv * g[13 + sy * 2];
        size_t oi = ((size_t)plane << 15) + ((size_t)(2 * y + sy) << 7) + xb;
        if (xf) {
          ((float2*)out)[oi] = make_float2(v0, v1);
        } else {
          union { bf16 hh2[2]; unsigned u; } pk;
          pk.hh2[0] = f2b(v0);
          pk.hh2[1] = f2b(v1);
          ((unsigned*)out)[oi] = pk.u;
        }
      }
    }
  }
}

extern "C" void kernel_launch(void* const* d_in, const int* in_sizes, int n_in,
                              void* d_out, int out_size, void* d_ws, size_t ws_size,
                              hipStream_t stream) {
  // Expected dict-order element counts:
  // x=33554432, wtf=4096, iwtf=4096, dww=6400, dwb=256, pw=65536, pb=256,
  // ab=512, bidx=4096
  const void *x, *wtf, *iwtf, *dww, *dwb, *pw, *pb, *ab;
  const int* bidx;
  if (in_sizes[0] == 33554432) {  // setup_inputs() dict order
    x = d_in[0]; wtf = d_in[1]; iwtf = d_in[2]; dww = d_in[3]; dwb = d_in[4];
    pw = d_in[5]; pb = d_in[6]; ab = d_in[7]; bidx = (const int*)d_in[8];
  } else if (in_sizes[0] == 512) {  // alphabetical order
    ab = d_in[0]; bidx = (const int*)d_in[1]; dwb = d_in[2]; dww = d_in[3];
    iwtf = d_in[4]; pb = d_in[5]; pw = d_in[6]; wtf = d_in[7]; x = d_in[8];
  } else {  // reversed dict order
    bidx = (const int*)d_in[0]; ab = d_in[1]; pb = d_in[2]; pw = d_in[3];
    dwb = d_in[4]; dww = d_in[5]; iwtf = d_in[6]; wtf = d_in[7]; x = d_in[8];
  }

  fused_kernel<<<512, 512, 0, stream>>>(x, wtf, iwtf, dww, dwb, pw, pb, ab,
                                        bidx, d_out);
}